// Round 4
// baseline (764.520 us; speedup 1.0000x reference)
//
#include <hip/hip_runtime.h>
#include <hip/hip_bf16.h>
#include <stdint.h>

#define D_DIM 256
#define INV_T 14.285714285714286f  // 1/0.07

#define BM 256
#define BN 256
#define BK 32
#define NSTEP (D_DIM / BK)  // 8

typedef __bf16 bf16x8 __attribute__((ext_vector_type(8)));
typedef float f32x16 __attribute__((ext_vector_type(16)));

// ---------------------------------------------------------------------------
// Kernel A: normalization. One wave per row (float4 loads), 4 rows/block.
// Exact fp32 diagonal Sv, bf16 normalized outputs, rowsum & done zero-init.
// ---------------------------------------------------------------------------
__global__ __launch_bounds__(256) void lit_normalize(
    const float* __restrict__ X, const float* __restrict__ Y,
    __hip_bfloat16* __restrict__ Xb, __hip_bfloat16* __restrict__ Yb,
    float* __restrict__ Sv, float* __restrict__ rowsum, unsigned* __restrict__ done)
{
    const int l = threadIdx.x & 63;
    const int row = blockIdx.x * 4 + (threadIdx.x >> 6);
    const size_t base = (size_t)row * D_DIM;
    const float4 x = ((const float4*)(X + base))[l];
    const float4 y = ((const float4*)(Y + base))[l];
    float nx = x.x * x.x + x.y * x.y + x.z * x.z + x.w * x.w;
    float ny = y.x * y.x + y.y * y.y + y.z * y.z + y.w * y.w;
    float dt = x.x * y.x + x.y * y.y + x.z * y.z + x.w * y.w;
    #pragma unroll
    for (int o = 1; o < 64; o <<= 1) {
        nx += __shfl_xor(nx, o);
        ny += __shfl_xor(ny, o);
        dt += __shfl_xor(dt, o);
    }
    const float ivx = 1.0f / fmaxf(sqrtf(nx), 1e-12f);
    const float ivy = 1.0f / fmaxf(sqrtf(ny), 1e-12f);

    __hip_bfloat16 hx0 = __float2bfloat16(x.x * ivx), hx1 = __float2bfloat16(x.y * ivx);
    __hip_bfloat16 hx2 = __float2bfloat16(x.z * ivx), hx3 = __float2bfloat16(x.w * ivx);
    __hip_bfloat16 hy0 = __float2bfloat16(y.x * ivy), hy1 = __float2bfloat16(y.y * ivy);
    __hip_bfloat16 hy2 = __float2bfloat16(y.z * ivy), hy3 = __float2bfloat16(y.w * ivy);
    ushort4 px, py;
    px.x = *(unsigned short*)&hx0; px.y = *(unsigned short*)&hx1;
    px.z = *(unsigned short*)&hx2; px.w = *(unsigned short*)&hx3;
    py.x = *(unsigned short*)&hy0; py.y = *(unsigned short*)&hy1;
    py.z = *(unsigned short*)&hy2; py.w = *(unsigned short*)&hy3;
    ((ushort4*)(Xb + base))[l] = px;
    ((ushort4*)(Yb + base))[l] = py;

    if (l == 0) {
        Sv[row] = (dt * ivx * ivy - 1.0f) * INV_T;  // exact diagonal logit
        rowsum[row] = 0.0f;
    }
    if (blockIdx.x == 0 && threadIdx.x == 0) done[0] = 0u;
}

// ---------------------------------------------------------------------------
// Kernel B: S = Xhat @ Yhat^T with swapped operands (D = mfma(Yf, Xf), so
// D[m=j][n=i] -> j-reduction is in-thread), fused exp/rowsum epilogue and
// last-block finalize.
// 256x256 tile, BK=32, 8 waves (wi=w>>2 over 2 i-halves of 128, wj=w&3 over
// 4 j-quarters of 64). 32x32x16 bf16 MFMA; acc[fj:2][fi:4].
// Pipeline: double-buffered 2x32KB LDS, stage-ahead-1, counted vmcnt(4),
// raw s_barrier (no vmcnt drain mid-loop), setprio around MFMA.
// LDS swizzle: physical slot = g ^ ((row>>1)&3), realized on the write side
// by pre-swizzling the global source (global_load_lds dest stays linear).
// ---------------------------------------------------------------------------
__global__ __launch_bounds__(512, 2) void lit_gemm_rowsum(
    const __hip_bfloat16* __restrict__ Xb, const __hip_bfloat16* __restrict__ Yb,
    const float* __restrict__ Sv, float* __restrict__ rowsum,
    unsigned* __restrict__ done, float* __restrict__ out, int N)
{
    __shared__ char lds[2 * 32768];  // [buf][X 16KB | Y 16KB]

    const int tid = (int)threadIdx.x;
    const int l   = tid & 63;
    const int w   = tid >> 6;    // 0..7
    const int wi  = w >> 2;      // 0..1  (i-half: 128 rows)
    const int wj  = w & 3;       // 0..3  (j-quarter: 64 rows)

    // XCD-aware bijective swizzle (nwg = 4096, %8 == 0)
    const int nx  = (int)gridDim.x;
    const int bid = (int)blockIdx.y * nx + (int)blockIdx.x;
    const int cpx = (nx * (int)gridDim.y) >> 3;
    const int logical = (bid & 7) * cpx + (bid >> 3);
    const int bi = logical / nx;
    const int bj = logical % nx;
    const int iBase = bi * BM;
    const int jBase = bj * BN;

    f32x16 acc[2][4];
    #pragma unroll
    for (int a = 0; a < 2; ++a)
        #pragma unroll
        for (int b = 0; b < 4; ++b)
            #pragma unroll
            for (int r = 0; r < 16; ++r)
                acc[a][b][r] = 0.f;

    // Staging: 32 chunks of 16 rows x 64B = 1KB; wave w owns chunks w*4..w*4+3.
    // Chunks 0..15 = X rows 0..255; chunks 16..31 = Y rows 0..255.
    const int rq = l >> 2;   // row within chunk
    const int sl = l & 3;    // 16B slot within a 64B row
    const char* src[4];
    int dst[4];
    #pragma unroll
    for (int c = 0; c < 4; ++c) {
        const int g    = w * 4 + c;
        const int isY  = g >> 4;
        const int r16  = (g & 15) * 16;
        const int row  = r16 + rq;
        const int slot = sl ^ ((row >> 1) & 3);  // pre-swizzled source slot
        const char* base = isY ? (const char*)Yb + (size_t)jBase * (D_DIM * 2)
                               : (const char*)Xb + (size_t)iBase * (D_DIM * 2);
        src[c] = base + (size_t)row * (D_DIM * 2) + slot * 16;
        dst[c] = isY * 16384 + r16 * 64;
    }

#define STAGE(buf, t)                                                              \
    {                                                                              \
        _Pragma("unroll")                                                          \
        for (int c = 0; c < 4; ++c)                                                \
            __builtin_amdgcn_global_load_lds(                                      \
                (const __attribute__((address_space(1))) void*)(src[c] + (t) * (BK * 2)), \
                (__attribute__((address_space(3))) void*)(lds + (buf) * 32768 + dst[c]),  \
                16, 0, 0);                                                         \
    }

    STAGE(0, 0);

    #pragma unroll
    for (int t = 0; t < NSTEP; ++t) {
        if (t < NSTEP - 1) {
            STAGE((t + 1) & 1, t + 1);                       // prefetch next tile
            asm volatile("s_waitcnt vmcnt(4)" ::: "memory"); // current tile landed
        } else {
            asm volatile("s_waitcnt vmcnt(0)" ::: "memory");
        }
        __builtin_amdgcn_sched_barrier(0);
        __builtin_amdgcn_s_barrier();   // all waves' staging for buf[t&1] visible

        const char* Xs = lds + (t & 1) * 32768;
        const char* Ys = Xs + 16384;
        const int lr = l & 31;
        #pragma unroll
        for (int kk = 0; kk < 2; ++kk) {
            // logical 16B k-slot g = kk*2 + (l>>5); physical = g ^ ((row>>1)&3)
            const int sx = ((kk * 2 + (l >> 5)) ^ ((l >> 1) & 3)) * 16;
            bf16x8 a0 = *(const bf16x8*)(Ys + (wj * 64 +  0 + lr) * 64 + sx);
            bf16x8 a1 = *(const bf16x8*)(Ys + (wj * 64 + 32 + lr) * 64 + sx);
            bf16x8 b0 = *(const bf16x8*)(Xs + (wi * 128 +  0 + lr) * 64 + sx);
            bf16x8 b1 = *(const bf16x8*)(Xs + (wi * 128 + 32 + lr) * 64 + sx);
            bf16x8 b2 = *(const bf16x8*)(Xs + (wi * 128 + 64 + lr) * 64 + sx);
            bf16x8 b3 = *(const bf16x8*)(Xs + (wi * 128 + 96 + lr) * 64 + sx);
            __builtin_amdgcn_s_setprio(1);
            acc[0][0] = __builtin_amdgcn_mfma_f32_32x32x16_bf16(a0, b0, acc[0][0], 0, 0, 0);
            acc[0][1] = __builtin_amdgcn_mfma_f32_32x32x16_bf16(a0, b1, acc[0][1], 0, 0, 0);
            acc[0][2] = __builtin_amdgcn_mfma_f32_32x32x16_bf16(a0, b2, acc[0][2], 0, 0, 0);
            acc[0][3] = __builtin_amdgcn_mfma_f32_32x32x16_bf16(a0, b3, acc[0][3], 0, 0, 0);
            acc[1][0] = __builtin_amdgcn_mfma_f32_32x32x16_bf16(a1, b0, acc[1][0], 0, 0, 0);
            acc[1][1] = __builtin_amdgcn_mfma_f32_32x32x16_bf16(a1, b1, acc[1][1], 0, 0, 0);
            acc[1][2] = __builtin_amdgcn_mfma_f32_32x32x16_bf16(a1, b2, acc[1][2], 0, 0, 0);
            acc[1][3] = __builtin_amdgcn_mfma_f32_32x32x16_bf16(a1, b3, acc[1][3], 0, 0, 0);
            __builtin_amdgcn_s_setprio(0);
        }
        __builtin_amdgcn_sched_barrier(0);
        __builtin_amdgcn_s_barrier();   // reads of buf[t&1] done -> safe to overwrite
    }

    // ---- epilogue: rowsum_i += sum_j exp((S[i][j]-1)/tau) ----
    // D layout (32x32): n=i = lane&31; m=j = (reg&3)+8*(reg>>2)+4*(lane>>5).
    float part[4];
    #pragma unroll
    for (int fi = 0; fi < 4; ++fi) {
        float s = 0.f;
        #pragma unroll
        for (int fj = 0; fj < 2; ++fj)
            #pragma unroll
            for (int r = 0; r < 16; ++r)
                s += __expf(fmaf(acc[fj][fi][r], INV_T, -INV_T));
        s += __shfl_xor(s, 32);
        part[fi] = s;
    }
    float* rowpart = (float*)lds;
    if (tid < BM) rowpart[tid] = 0.f;
    __syncthreads();
    if (l < 32) {
        #pragma unroll
        for (int fi = 0; fi < 4; ++fi)
            atomicAdd(&rowpart[wi * 128 + fi * 32 + l], part[fi]);
    }
    __syncthreads();
    if (tid < BM) atomicAdd(&rowsum[iBase + tid], rowpart[tid]);

    // ---- fused finalize: last block computes -mean(Sv - log(rowsum)) ----
    __threadfence();   // order rowsum atomics before the counter increment
    __syncthreads();
    __shared__ unsigned lastBlock;
    if (tid == 0) {
        unsigned old = atomicAdd(done, 1u);
        lastBlock = (old == (unsigned)(gridDim.x * gridDim.y) - 1u) ? 1u : 0u;
        if (lastBlock) __threadfence();  // acquire: rowsum atomics from all blocks
    }
    __syncthreads();
    if (lastBlock) {
        float s = 0.f;
        for (int r = tid; r < N; r += 512) {
            float rs = __hip_atomic_load(&rowsum[r], __ATOMIC_RELAXED, __HIP_MEMORY_SCOPE_AGENT);
            s += Sv[r] - __logf(rs);
        }
        #pragma unroll
        for (int o = 1; o < 64; o <<= 1) s += __shfl_xor(s, o);
        __shared__ float fr[8];
        if ((tid & 63) == 0) fr[tid >> 6] = s;
        __syncthreads();
        if (tid == 0) {
            float tot = 0.f;
            #pragma unroll
            for (int k = 0; k < 8; ++k) tot += fr[k];
            out[0] = -tot / (float)N;
        }
    }
}

// ---------------------------------------------------------------------------
extern "C" void kernel_launch(void* const* d_in, const int* in_sizes, int n_in,
                              void* d_out, int out_size, void* d_ws, size_t ws_size,
                              hipStream_t stream)
{
    const float* X = (const float*)d_in[0];
    const float* Y = (const float*)d_in[1];
    const int N = in_sizes[0] / D_DIM;  // 16384

    char* ws = (char*)d_ws;
    __hip_bfloat16* Xb = (__hip_bfloat16*)ws;
    __hip_bfloat16* Yb = (__hip_bfloat16*)(ws + (size_t)N * D_DIM * 2);
    float* Sv       = (float*)(ws + (size_t)N * D_DIM * 4);
    float* rowsum   = (float*)(ws + (size_t)N * D_DIM * 4 + (size_t)N * 4);
    unsigned* done  = (unsigned*)(ws + (size_t)N * D_DIM * 4 + (size_t)N * 8);

    lit_normalize<<<N / 4, 256, 0, stream>>>(X, Y, Xb, Yb, Sv, rowsum, done);
    dim3 grid(N / BN, N / BM);
    lit_gemm_rowsum<<<grid, 512, 0, stream>>>(Xb, Yb, Sv, rowsum, done, (float*)d_out, N);
}